// Round 2
// baseline (220.690 us; speedup 1.0000x reference)
//
#include <hip/hip_runtime.h>

// out = SEQ*(X@Wv + bv)@Wo + bo  (reference's softmax weights sum to SEQ exactly).
// Wc = SEQ*(Wv@Wo) [512x512]; cvec = SEQ*(bv@Wo); out = X@Wc + cvec + bo.
// Round 2: XCD swizzle (T1) + async-stage double-buffered LDS (T14).

#define DM    512
#define HC    4096
#define SEQF  2048.0f
#define MROWS 4096

// ---------------- Kernel A: Wc += SEQ * Wv@Wo -------------------------------
// 64x64 tile, 4x4/thread, 256 threads. Grid 512 blocks = (8 n) x (8 i) x (8 kc),
// K-chunk = 512 (16 staging iters of 32). XCD swizzle groups the 64 blocks of
// one k-chunk (which share 2 MB of A/B slices) onto one XCD's L2.
__global__ __launch_bounds__(256) void gemm_wc(const float* __restrict__ Wv,
                                               const float* __restrict__ Wo,
                                               float* __restrict__ Wc) {
    __shared__ float As[2][32][68];  // [buf][j][i]
    __shared__ float Bs[2][32][68];  // [buf][j][n]
    const int d   = blockIdx.x;                 // 0..511, xcd = d%8 (round-robin)
    const int lin = (d & 7) * 64 + (d >> 3);    // bijection: one xcd = 64 consecutive lins
    const int x = lin & 7, y = (lin >> 3) & 7, z = lin >> 6;
    const int i0 = y * 64, n0 = x * 64, jbase = z * 512;
    const int tid = threadIdx.x, tx = tid & 15, ty = tid >> 4;

    const int ar = tid >> 3, ac = (tid & 7) * 4;    // A stage: row 0..31(+32), col4
    const int br = tid >> 4, bc = (tid & 15) * 4;   // B stage: row 0..15(+16), col4

    float4 ra0, ra1, rb0, rb1;
    auto load = [&](int t) {
        const int j0 = jbase + t * 32;
        ra0 = *reinterpret_cast<const float4*>(&Wv[(size_t)(i0 + ar) * HC + j0 + ac]);
        ra1 = *reinterpret_cast<const float4*>(&Wv[(size_t)(i0 + ar + 32) * HC + j0 + ac]);
        rb0 = *reinterpret_cast<const float4*>(&Wo[(size_t)(j0 + br) * DM + n0 + bc]);
        rb1 = *reinterpret_cast<const float4*>(&Wo[(size_t)(j0 + br + 16) * DM + n0 + bc]);
    };
    auto store = [&](int b) {
        As[b][ac + 0][ar] = ra0.x; As[b][ac + 1][ar] = ra0.y;
        As[b][ac + 2][ar] = ra0.z; As[b][ac + 3][ar] = ra0.w;
        As[b][ac + 0][ar + 32] = ra1.x; As[b][ac + 1][ar + 32] = ra1.y;
        As[b][ac + 2][ar + 32] = ra1.z; As[b][ac + 3][ar + 32] = ra1.w;
        *reinterpret_cast<float4*>(&Bs[b][br][bc]) = rb0;
        *reinterpret_cast<float4*>(&Bs[b][br + 16][bc]) = rb1;
    };

    load(0); store(0); __syncthreads();
    float acc[4][4] = {};
    for (int t = 0; t < 16; ++t) {
        const int cur = t & 1;
        if (t + 1 < 16) load(t + 1);    // issue early; vmcnt waited at store()
#pragma unroll
        for (int kk = 0; kk < 32; ++kk) {
            const float4 a = *reinterpret_cast<const float4*>(&As[cur][kk][ty * 4]);
            const float4 b = *reinterpret_cast<const float4*>(&Bs[cur][kk][tx * 4]);
            const float av[4] = {a.x, a.y, a.z, a.w};
            const float bw[4] = {b.x, b.y, b.z, b.w};
#pragma unroll
            for (int r = 0; r < 4; ++r)
#pragma unroll
                for (int c = 0; c < 4; ++c)
                    acc[r][c] = fmaf(av[r], bw[c], acc[r][c]);
        }
        if (t + 1 < 16) store(cur ^ 1); // write-late into the idle buffer
        __syncthreads();
    }
#pragma unroll
    for (int r = 0; r < 4; ++r)
#pragma unroll
        for (int c = 0; c < 4; ++c)
            atomicAdd(&Wc[(size_t)(i0 + ty * 4 + r) * DM + n0 + tx * 4 + c],
                      SEQF * acc[r][c]);
}

// ---------------- Bias: cvec[n] += SEQ * sum_j bv[j]*Wo[j][n] ----------------
__global__ __launch_bounds__(512) void bias_c(const float* __restrict__ bv,
                                              const float* __restrict__ Wo,
                                              float* __restrict__ cvec) {
    const int n  = threadIdx.x;
    const int j0 = blockIdx.x * 128;
    float s = 0.f;
    for (int j = j0; j < j0 + 128; ++j)
        s = fmaf(bv[j], Wo[(size_t)j * DM + n], s);
    atomicAdd(&cvec[n], SEQF * s);
}

// ---------------- Kernel B: out = X@Wc + cvec + bo ---------------------------
// 64x64 tile, 4x4/thread, K=512 (16 iters). Grid 512 = (8 n) x (64 m).
// Swizzle: one xcd = 8 m-tiles x 8 n-tiles -> X tiles 1 MB + Wc 1 MB in its L2.
__global__ __launch_bounds__(256) void gemm_out(const float* __restrict__ X,
                                                const float* __restrict__ Wc,
                                                const float* __restrict__ cvec,
                                                const float* __restrict__ bo,
                                                float* __restrict__ out) {
    __shared__ float As[2][32][68];  // [buf][k][m]
    __shared__ float Bs[2][32][68];  // [buf][k][n]
    const int d   = blockIdx.x;                 // 0..511
    const int lin = (d & 7) * 64 + (d >> 3);
    const int x = lin & 7, y = lin >> 3;        // n-tile, m-tile
    const int m0 = y * 64, n0 = x * 64;
    const int tid = threadIdx.x, tx = tid & 15, ty = tid >> 4;

    const int ar = tid >> 3, ac = (tid & 7) * 4;
    const int br = tid >> 4, bc = (tid & 15) * 4;

    float4 ra0, ra1, rb0, rb1;
    auto load = [&](int t) {
        const int k0 = t * 32;
        ra0 = *reinterpret_cast<const float4*>(&X[(size_t)(m0 + ar) * DM + k0 + ac]);
        ra1 = *reinterpret_cast<const float4*>(&X[(size_t)(m0 + ar + 32) * DM + k0 + ac]);
        rb0 = *reinterpret_cast<const float4*>(&Wc[(size_t)(k0 + br) * DM + n0 + bc]);
        rb1 = *reinterpret_cast<const float4*>(&Wc[(size_t)(k0 + br + 16) * DM + n0 + bc]);
    };
    auto store = [&](int b) {
        As[b][ac + 0][ar] = ra0.x; As[b][ac + 1][ar] = ra0.y;
        As[b][ac + 2][ar] = ra0.z; As[b][ac + 3][ar] = ra0.w;
        As[b][ac + 0][ar + 32] = ra1.x; As[b][ac + 1][ar + 32] = ra1.y;
        As[b][ac + 2][ar + 32] = ra1.z; As[b][ac + 3][ar + 32] = ra1.w;
        *reinterpret_cast<float4*>(&Bs[b][br][bc]) = rb0;
        *reinterpret_cast<float4*>(&Bs[b][br + 16][bc]) = rb1;
    };

    load(0); store(0); __syncthreads();
    float acc[4][4] = {};
    for (int t = 0; t < 16; ++t) {
        const int cur = t & 1;
        if (t + 1 < 16) load(t + 1);
#pragma unroll
        for (int kk = 0; kk < 32; ++kk) {
            const float4 a = *reinterpret_cast<const float4*>(&As[cur][kk][ty * 4]);
            const float4 b = *reinterpret_cast<const float4*>(&Bs[cur][kk][tx * 4]);
            const float av[4] = {a.x, a.y, a.z, a.w};
            const float bw[4] = {b.x, b.y, b.z, b.w};
#pragma unroll
            for (int r = 0; r < 4; ++r)
#pragma unroll
                for (int c = 0; c < 4; ++c)
                    acc[r][c] = fmaf(av[r], bw[c], acc[r][c]);
        }
        if (t + 1 < 16) store(cur ^ 1);
        __syncthreads();
    }
    const float4 cv = *reinterpret_cast<const float4*>(&cvec[n0 + tx * 4]);
    const float4 bb = *reinterpret_cast<const float4*>(&bo[n0 + tx * 4]);
#pragma unroll
    for (int r = 0; r < 4; ++r) {
        const int m = m0 + ty * 4 + r;
        float4 o;
        o.x = acc[r][0] + cv.x + bb.x;
        o.y = acc[r][1] + cv.y + bb.y;
        o.z = acc[r][2] + cv.z + bb.z;
        o.w = acc[r][3] + cv.w + bb.w;
        *reinterpret_cast<float4*>(&out[(size_t)m * DM + n0 + tx * 4]) = o;
    }
}

extern "C" void kernel_launch(void* const* d_in, const int* in_sizes, int n_in,
                              void* d_out, int out_size, void* d_ws, size_t ws_size,
                              hipStream_t stream) {
    // inputs: 0 input, 1 mask, 2 Wq, 3 bq, 4 Wk, 5 bk, 6 Wv, 7 bv, 8 Wo, 9 bo
    const float* input = (const float*)d_in[0];
    const float* Wv    = (const float*)d_in[6];
    const float* bv    = (const float*)d_in[7];
    const float* Wo    = (const float*)d_in[8];
    const float* bo    = (const float*)d_in[9];
    float* out = (float*)d_out;

    float* Wc   = (float*)d_ws;            // 512*512
    float* cvec = Wc + DM * DM;            // 512
    hipMemsetAsync(d_ws, 0, (size_t)(DM * DM + DM) * sizeof(float), stream);

    gemm_wc<<<512, 256, 0, stream>>>(Wv, Wo, Wc);
    bias_c<<<32, 512, 0, stream>>>(bv, Wo, cvec);
    gemm_out<<<512, 256, 0, stream>>>(input, Wc, cvec, bo, out);
}

// Round 3
// 156.604 us; speedup vs baseline: 1.4092x; 1.4092x over previous
//
#include <hip/hip_runtime.h>

// out = SEQ*(X@Wv + bv)@Wo + bo   (reference's softmax weights sum to SEQ exactly;
// Q/K/mask/softmax are dead code under the 'nhkq,nvhd->nvhd' einsum quirk).
// WcT[n][i] = SEQ*sum_j Wo[j][n]*Wv[i][j];  out[m][n] = sum_i X[m][i]*WcT[n][i] + cvec[n] + bo[n].
// Round 3: split-bf16 MFMA (hi+lo, 3 terms: err ~2^-16 rel, absmax budget is 32).
// ws: WoT_hi|WoT_lo (4MB+4MB) | WcT f32 (1MB) | WcT_hi|lo (0.5+0.5MB) | cvec (2KB) ~= 10.5MB.

#define DM 512
#define HC 4096
#define SEQF 2048.0f

typedef short bf16x8 __attribute__((ext_vector_type(8)));
typedef float f32x4 __attribute__((ext_vector_type(4)));

#define LDR 40  // LDS row stride (ushorts): 80 B rows -> 16B-aligned, <=2-way bank conflict

// x -> hi(bf16 trunc) + lo(bf16 trunc of residual); |x - hi - lo| <= ~2^-16 |x|
__device__ __forceinline__ void split2(float x, ushort& h, ushort& l) {
    unsigned b = __float_as_uint(x);
    h = (ushort)(b >> 16);
    float hf = __uint_as_float((unsigned)(h) << 16);
    l = (ushort)(__float_as_uint(x - hf) >> 16);
}

// Stage ROWS x 32 fp32 tile -> LDS bf16 hi/lo (K-contiguous rows).
template <int ROWS>
__device__ __forceinline__ void stage_f32(const float* __restrict__ src, int ld, int row0,
                                          int k0, ushort* Hh, ushort* Hl, int tid) {
    const int r   = (ROWS == 128) ? (tid >> 1) : (tid >> 2);
    const int co  = (ROWS == 128) ? ((tid & 1) * 16) : ((tid & 3) * 8);
    const int NF4 = (ROWS == 128) ? 4 : 2;
    const float* p = src + (size_t)(row0 + r) * ld + k0 + co;
#pragma unroll
    for (int c = 0; c < NF4; ++c) {
        float4 v = *reinterpret_cast<const float4*>(p + c * 4);
        ushort4 uh, ul;
        split2(v.x, uh.x, ul.x);
        split2(v.y, uh.y, ul.y);
        split2(v.z, uh.z, ul.z);
        split2(v.w, uh.w, ul.w);
        *reinterpret_cast<ushort4*>(&Hh[r * LDR + co + c * 4]) = uh;
        *reinterpret_cast<ushort4*>(&Hl[r * LDR + co + c * 4]) = ul;
    }
}

// Stage ROWS x 32 pre-split bf16 tile (hi/lo in global) -> LDS.
template <int ROWS>
__device__ __forceinline__ void stage_bf16(const ushort* __restrict__ srcH,
                                           const ushort* __restrict__ srcL, int ld, int row0,
                                           int k0, ushort* Hh, ushort* Hl, int tid) {
    const int r   = (ROWS == 128) ? (tid >> 1) : (tid >> 2);
    const int co  = (ROWS == 128) ? ((tid & 1) * 16) : ((tid & 3) * 8);
    const int NI4 = (ROWS == 128) ? 2 : 1;
    const size_t off = (size_t)(row0 + r) * ld + k0 + co;
#pragma unroll
    for (int c = 0; c < NI4; ++c) {
        *reinterpret_cast<int4*>(&Hh[r * LDR + co + c * 8]) =
            *reinterpret_cast<const int4*>(&srcH[off + c * 8]);
        *reinterpret_cast<int4*>(&Hl[r * LDR + co + c * 8]) =
            *reinterpret_cast<const int4*>(&srcL[off + c * 8]);
    }
}

// ---- prep_wo: Wo[4096][512] fp32 -> WoT hi/lo [512][4096] bf16; fused cvec reduction ----
__global__ __launch_bounds__(256) void prep_wo(const float* __restrict__ Wo,
                                               const float* __restrict__ bv,
                                               ushort* __restrict__ WoTh,
                                               ushort* __restrict__ WoTl,
                                               float* __restrict__ cvec) {
    __shared__ float T[64][65];
    const int bj = blockIdx.x;  // 64 j-tiles
    const int bn = blockIdx.y;  // 8 n-tiles
    const int tid = threadIdx.x;
    {
        const int r = tid >> 2, c16 = (tid & 3) * 16;
        const float* p = Wo + (size_t)(bj * 64 + r) * DM + bn * 64 + c16;
#pragma unroll
        for (int c = 0; c < 4; ++c) {
            float4 v = *reinterpret_cast<const float4*>(p + c * 4);
            T[r][c16 + c * 4 + 0] = v.x;
            T[r][c16 + c * 4 + 1] = v.y;
            T[r][c16 + c * 4 + 2] = v.z;
            T[r][c16 + c * 4 + 3] = v.w;
        }
    }
    __syncthreads();
    {   // transposed write: WoT row n = bn*64+rn, cols bj*64 + c16..+15
        const int rn = tid >> 2, c16 = (tid & 3) * 16;
        const size_t off = (size_t)(bn * 64 + rn) * HC + bj * 64 + c16;
#pragma unroll
        for (int q = 0; q < 4; ++q) {
            ushort4 uh, ul;
            split2(T[c16 + q * 4 + 0][rn], uh.x, ul.x);
            split2(T[c16 + q * 4 + 1][rn], uh.y, ul.y);
            split2(T[c16 + q * 4 + 2][rn], uh.z, ul.z);
            split2(T[c16 + q * 4 + 3][rn], uh.w, ul.w);
            *reinterpret_cast<ushort4*>(&WoTh[off + q * 4]) = uh;
            *reinterpret_cast<ushort4*>(&WoTl[off + q * 4]) = ul;
        }
    }
    // fused: cvec[n] += SEQ * sum_j bv[j]*Wo[j][n] (partial over this j-tile)
    if (tid < 64) {
        float s = 0.f;
#pragma unroll 8
        for (int j = 0; j < 64; ++j) s = fmaf(bv[bj * 64 + j], T[j][tid], s);
        atomicAdd(&cvec[bn * 64 + tid], SEQF * s);
    }
}

// ---- gemm_wcT: WcT[n][i] += SEQ * sum_k WoT[n][k]*Wv[i][k]  (A=WoT bf16, B=Wv fp32) ----
// 128x128 tile, 4 waves (2x2 of 64x64), BK=32, split-K 16 -> 256 blocks, fp32 atomics.
__global__ __launch_bounds__(256) void gemm_wcT(const ushort* __restrict__ WoTh,
                                                const ushort* __restrict__ WoTl,
                                                const float* __restrict__ Wv,
                                                float* __restrict__ WcT) {
    __shared__ ushort Ah[128 * LDR], Al[128 * LDR], Bh[128 * LDR], Bl[128 * LDR];
    const int d = blockIdx.x;  // 0..255
    const int lin = (d & 7) * 32 + (d >> 3);      // one XCD = 2 consecutive k-chunks
    const int kc = lin >> 4, mt = (lin >> 2) & 3, nt = lin & 3;
    const int a0 = mt * 128, b0 = nt * 128, kbase = kc * 256;
    const int tid = threadIdx.x, wave = tid >> 6, lane = tid & 63;
    const int wm = (wave >> 1) * 64, wn = (wave & 1) * 64;
    const int fr = lane & 15, fs = (lane >> 4) * 8;

    f32x4 acc[4][4] = {};
    for (int t = 0; t < 8; ++t) {
        const int k0 = kbase + t * 32;
        stage_bf16<128>(WoTh, WoTl, HC, a0, k0, Ah, Al, tid);
        stage_f32<128>(Wv, HC, b0, k0, Bh, Bl, tid);
        __syncthreads();
        bf16x8 afh[4], afl[4], bfh[4], bfl[4];
#pragma unroll
        for (int f = 0; f < 4; ++f) {
            const int ai = (wm + f * 16 + fr) * LDR + fs;
            afh[f] = *reinterpret_cast<const bf16x8*>(&Ah[ai]);
            afl[f] = *reinterpret_cast<const bf16x8*>(&Al[ai]);
            const int bi = (wn + f * 16 + fr) * LDR + fs;
            bfh[f] = *reinterpret_cast<const bf16x8*>(&Bh[bi]);
            bfl[f] = *reinterpret_cast<const bf16x8*>(&Bl[bi]);
        }
#pragma unroll
        for (int f = 0; f < 4; ++f)
#pragma unroll
            for (int g = 0; g < 4; ++g) {
                acc[f][g] = __builtin_amdgcn_mfma_f32_16x16x32_bf16(afh[f], bfh[g], acc[f][g], 0, 0, 0);
                acc[f][g] = __builtin_amdgcn_mfma_f32_16x16x32_bf16(afh[f], bfl[g], acc[f][g], 0, 0, 0);
                acc[f][g] = __builtin_amdgcn_mfma_f32_16x16x32_bf16(afl[f], bfh[g], acc[f][g], 0, 0, 0);
            }
        __syncthreads();
    }
#pragma unroll
    for (int f = 0; f < 4; ++f)
#pragma unroll
        for (int g = 0; g < 4; ++g)
#pragma unroll
            for (int q = 0; q < 4; ++q) {
                const int row = a0 + wm + f * 16 + (lane >> 4) * 4 + q;
                const int col = b0 + wn + g * 16 + (lane & 15);
                atomicAdd(&WcT[(size_t)row * DM + col], SEQF * acc[f][g][q]);
            }
}

// ---- prep_wct: WcT fp32 [512][512] -> hi/lo bf16 ----
__global__ __launch_bounds__(256) void prep_wct(const float* __restrict__ WcT,
                                                ushort* __restrict__ WcTh,
                                                ushort* __restrict__ WcTl) {
    const int i = blockIdx.x * 256 + threadIdx.x;  // 256 blocks * 256 thr * 4 = 512*512
    const float4 v = reinterpret_cast<const float4*>(WcT)[i];
    ushort4 uh, ul;
    split2(v.x, uh.x, ul.x);
    split2(v.y, uh.y, ul.y);
    split2(v.z, uh.z, ul.z);
    split2(v.w, uh.w, ul.w);
    reinterpret_cast<ushort4*>(WcTh)[i] = uh;
    reinterpret_cast<ushort4*>(WcTl)[i] = ul;
}

// ---- gemm_out: out[m][n] = sum_i X[m][i]*WcT[n][i] + cvec[n] + bo[n] ----
// 64x128 tile (A=X fp32 64 rows, B=WcT bf16 128 rows), 4 waves (2x2 of 32x64), K=512.
__global__ __launch_bounds__(256) void gemm_out(const float* __restrict__ X,
                                                const ushort* __restrict__ WcTh,
                                                const ushort* __restrict__ WcTl,
                                                const float* __restrict__ cvec,
                                                const float* __restrict__ bo,
                                                float* __restrict__ out) {
    __shared__ ushort Ah[64 * LDR], Al[64 * LDR], Bh[128 * LDR], Bl[128 * LDR];
    const int d = blockIdx.x;  // 0..255
    const int lin = (d & 7) * 32 + (d >> 3);  // group same-n panels per XCD
    const int nt = lin >> 6, mt = lin & 63;
    const int a0 = mt * 64, b0 = nt * 128;
    const int tid = threadIdx.x, wave = tid >> 6, lane = tid & 63;
    const int wm = (wave >> 1) * 32, wn = (wave & 1) * 64;
    const int fr = lane & 15, fs = (lane >> 4) * 8;

    f32x4 acc[2][4] = {};
    for (int t = 0; t < 16; ++t) {
        const int k0 = t * 32;
        stage_f32<64>(X, DM, a0, k0, Ah, Al, tid);
        stage_bf16<128>(WcTh, WcTl, DM, b0, k0, Bh, Bl, tid);
        __syncthreads();
        bf16x8 afh[2], afl[2], bfh[4], bfl[4];
#pragma unroll
        for (int f = 0; f < 2; ++f) {
            const int ai = (wm + f * 16 + fr) * LDR + fs;
            afh[f] = *reinterpret_cast<const bf16x8*>(&Ah[ai]);
            afl[f] = *reinterpret_cast<const bf16x8*>(&Al[ai]);
        }
#pragma unroll
        for (int g = 0; g < 4; ++g) {
            const int bi = (wn + g * 16 + fr) * LDR + fs;
            bfh[g] = *reinterpret_cast<const bf16x8*>(&Bh[bi]);
            bfl[g] = *reinterpret_cast<const bf16x8*>(&Bl[bi]);
        }
#pragma unroll
        for (int f = 0; f < 2; ++f)
#pragma unroll
            for (int g = 0; g < 4; ++g) {
                acc[f][g] = __builtin_amdgcn_mfma_f32_16x16x32_bf16(afh[f], bfh[g], acc[f][g], 0, 0, 0);
                acc[f][g] = __builtin_amdgcn_mfma_f32_16x16x32_bf16(afh[f], bfl[g], acc[f][g], 0, 0, 0);
                acc[f][g] = __builtin_amdgcn_mfma_f32_16x16x32_bf16(afl[f], bfh[g], acc[f][g], 0, 0, 0);
            }
        __syncthreads();
    }
#pragma unroll
    for (int g = 0; g < 4; ++g) {
        const int n = b0 + wn + g * 16 + (lane & 15);
        const float cb = cvec[n] + bo[n];
#pragma unroll
        for (int f = 0; f < 2; ++f)
#pragma unroll
            for (int q = 0; q < 4; ++q) {
                const int m = a0 + wm + f * 16 + (lane >> 4) * 4 + q;
                out[(size_t)m * DM + n] = acc[f][g][q] + cb;
            }
    }
}

extern "C" void kernel_launch(void* const* d_in, const int* in_sizes, int n_in,
                              void* d_out, int out_size, void* d_ws, size_t ws_size,
                              hipStream_t stream) {
    // inputs: 0 input, 1 mask, 2 Wq, 3 bq, 4 Wk, 5 bk, 6 Wv, 7 bv, 8 Wo, 9 bo
    const float* input = (const float*)d_in[0];
    const float* Wv    = (const float*)d_in[6];
    const float* bv    = (const float*)d_in[7];
    const float* Wo    = (const float*)d_in[8];
    const float* bo    = (const float*)d_in[9];
    float* out = (float*)d_out;

    ushort* WoTh = (ushort*)d_ws;                       // 512*4096 bf16 = 4 MB
    ushort* WoTl = WoTh + (size_t)DM * HC;              // 4 MB
    float*  WcT  = (float*)(WoTl + (size_t)DM * HC);    // 1 MB fp32
    ushort* WcTh = (ushort*)(WcT + DM * DM);            // 0.5 MB
    ushort* WcTl = WcTh + DM * DM;                      // 0.5 MB
    float*  cvec = (float*)(WcTl + DM * DM);            // 2 KB

    // zero the accumulated regions (WcT + cvec; covers WcTh/l harmlessly in between)
    hipMemsetAsync(WcT, 0, (size_t)DM * DM * 8 + DM * 4, stream);

    prep_wo<<<dim3(64, 8), 256, 0, stream>>>(Wo, bv, WoTh, WoTl, cvec);
    gemm_wcT<<<256, 256, 0, stream>>>(WoTh, WoTl, Wv, WcT);
    prep_wct<<<256, 256, 0, stream>>>(WcT, WcTh, WcTl);
    gemm_out<<<256, 256, 0, stream>>>(input, WcTh, WcTl, cvec, bo, out);
}

// Round 4
// 154.430 us; speedup vs baseline: 1.4291x; 1.0141x over previous
//
#include <hip/hip_runtime.h>

// out = SEQ*(X@Wv + bv)@Wo + bo   (reference's 'nhkq,nvhd->nvhd' einsum reduces the
// softmax weights over BOTH seq axes; each row sums to 1 -> scalar SEQ per (n,h);
// Q/K/mask/softmax are dead code).
// WcT[n][i] = SEQ*sum_j Wo[j][n]*Wv[i][j]; cvec = SEQ*bv@Wo;
// out[m][n] = sum_i X[m][i]*WcT[n][i] + cvec[n] + bo[n].
// Split-bf16 MFMA (x = hi + lo; 3 terms hH+hL+lH -> rel err ~2^-16, absmax budget 32).
// Round 4: 64x64 tiles / 512-block grids (2 blocks/CU), prep_wct folded into gemm_out.
// ws: WoTh (4MB) | WoTl (4MB) | WcT f32 (1MB) | cvec (2KB).

#define DM 512
#define HC 4096
#define SEQF 2048.0f
#define LDR 40  // LDS row stride in ushorts: 80B rows, 16B-aligned, 2-way conflicts max

typedef short bf16x8 __attribute__((ext_vector_type(8)));
typedef float f32x4 __attribute__((ext_vector_type(4)));

__device__ __forceinline__ void split2(float x, ushort& h, ushort& l) {
    unsigned b = __float_as_uint(x);
    h = (ushort)(b >> 16);
    float hf = __uint_as_float((unsigned)h << 16);
    l = (ushort)(__float_as_uint(x - hf) >> 16);
}

// stage 64 rows x 32 k: fp32 global -> split bf16 hi/lo in LDS
__device__ __forceinline__ void stage64_f32(const float* __restrict__ src, int ld,
                                            int row0, int k0, ushort* Hh, ushort* Hl,
                                            int tid) {
    const int r = tid >> 2, co = (tid & 3) * 8;
    const float* p = src + (size_t)(row0 + r) * ld + k0 + co;
    const float4 v0 = *reinterpret_cast<const float4*>(p);
    const float4 v1 = *reinterpret_cast<const float4*>(p + 4);
    ushort4 h0, l0, h1, l1;
    split2(v0.x, h0.x, l0.x); split2(v0.y, h0.y, l0.y);
    split2(v0.z, h0.z, l0.z); split2(v0.w, h0.w, l0.w);
    split2(v1.x, h1.x, l1.x); split2(v1.y, h1.y, l1.y);
    split2(v1.z, h1.z, l1.z); split2(v1.w, h1.w, l1.w);
    *reinterpret_cast<ushort4*>(&Hh[r * LDR + co])     = h0;
    *reinterpret_cast<ushort4*>(&Hh[r * LDR + co + 4]) = h1;
    *reinterpret_cast<ushort4*>(&Hl[r * LDR + co])     = l0;
    *reinterpret_cast<ushort4*>(&Hl[r * LDR + co + 4]) = l1;
}

// stage 64 rows x 32 k: pre-split bf16 hi/lo global -> LDS
__device__ __forceinline__ void stage64_bf16(const ushort* __restrict__ sh,
                                             const ushort* __restrict__ sl, int ld,
                                             int row0, int k0, ushort* Hh, ushort* Hl,
                                             int tid) {
    const int r = tid >> 2, co = (tid & 3) * 8;
    const size_t off = (size_t)(row0 + r) * ld + k0 + co;
    *reinterpret_cast<int4*>(&Hh[r * LDR + co]) = *reinterpret_cast<const int4*>(&sh[off]);
    *reinterpret_cast<int4*>(&Hl[r * LDR + co]) = *reinterpret_cast<const int4*>(&sl[off]);
}

// ---- prep_wo: Wo[4096][512] fp32 -> WoT hi/lo [512][4096] bf16; fused cvec ----
__global__ __launch_bounds__(256) void prep_wo(const float* __restrict__ Wo,
                                               const float* __restrict__ bv,
                                               ushort* __restrict__ WoTh,
                                               ushort* __restrict__ WoTl,
                                               float* __restrict__ cvec) {
    __shared__ float T[64][65];
    const int bj = blockIdx.x;  // 64 j-tiles
    const int bn = blockIdx.y;  // 8 n-tiles
    const int tid = threadIdx.x;
    {
        const int r = tid >> 2, c16 = (tid & 3) * 16;
        const float* p = Wo + (size_t)(bj * 64 + r) * DM + bn * 64 + c16;
#pragma unroll
        for (int c = 0; c < 4; ++c) {
            float4 v = *reinterpret_cast<const float4*>(p + c * 4);
            T[r][c16 + c * 4 + 0] = v.x;
            T[r][c16 + c * 4 + 1] = v.y;
            T[r][c16 + c * 4 + 2] = v.z;
            T[r][c16 + c * 4 + 3] = v.w;
        }
    }
    __syncthreads();
    {   // transposed write: WoT row n = bn*64+rn, cols bj*64 + c16..+15
        const int rn = tid >> 2, c16 = (tid & 3) * 16;
        const size_t off = (size_t)(bn * 64 + rn) * HC + bj * 64 + c16;
#pragma unroll
        for (int q = 0; q < 4; ++q) {
            ushort4 uh, ul;
            split2(T[c16 + q * 4 + 0][rn], uh.x, ul.x);
            split2(T[c16 + q * 4 + 1][rn], uh.y, ul.y);
            split2(T[c16 + q * 4 + 2][rn], uh.z, ul.z);
            split2(T[c16 + q * 4 + 3][rn], uh.w, ul.w);
            *reinterpret_cast<ushort4*>(&WoTh[off + q * 4]) = uh;
            *reinterpret_cast<ushort4*>(&WoTl[off + q * 4]) = ul;
        }
    }
    if (tid < 64) {  // cvec[n] += SEQ * sum_j bv[j]*Wo[j][n], partial over j-tile
        float s = 0.f;
#pragma unroll 8
        for (int j = 0; j < 64; ++j) s = fmaf(bv[bj * 64 + j], T[j][tid], s);
        atomicAdd(&cvec[bn * 64 + tid], SEQF * s);
    }
}

// ---- gemm_wcT: WcT[n][i] += SEQ * sum_k WoT[n][k]*Wv[i][k] ----
// 64x64 tile, 4 waves (one 16-row stripe each), BK=32, split-K 8 -> 512 blocks.
// Swizzle: XCD x owns k-chunk x (all 64 tiles) -> 2 MB L2-resident slices.
__global__ __launch_bounds__(256) void gemm_wcT(const ushort* __restrict__ WoTh,
                                                const ushort* __restrict__ WoTl,
                                                const float* __restrict__ Wv,
                                                float* __restrict__ WcT) {
    __shared__ ushort Ah[64 * LDR], Al[64 * LDR], Bh[64 * LDR], Bl[64 * LDR];
    const int d = blockIdx.x;                  // 0..511
    const int lin = (d & 7) * 64 + (d >> 3);   // bijective; xcd = d%8 = lin/64
    const int kc = lin >> 6, tile = lin & 63;
    const int nt = tile >> 3, it = tile & 7;
    const int a0 = nt * 64, b0 = it * 64, kb = kc * 512;
    const int tid = threadIdx.x, wave = tid >> 6, lane = tid & 63;
    const int wm = wave * 16, fr = lane & 15, fs = (lane >> 4) * 8;

    f32x4 acc[4] = {};
    for (int t = 0; t < 16; ++t) {
        const int k0 = kb + t * 32;
        stage64_bf16(WoTh, WoTl, HC, a0, k0, Ah, Al, tid);
        stage64_f32(Wv, HC, b0, k0, Bh, Bl, tid);
        __syncthreads();
        const int ai = (wm + fr) * LDR + fs;
        const bf16x8 ah = *reinterpret_cast<const bf16x8*>(&Ah[ai]);
        const bf16x8 al = *reinterpret_cast<const bf16x8*>(&Al[ai]);
#pragma unroll
        for (int g = 0; g < 4; ++g) {
            const int bi = (g * 16 + fr) * LDR + fs;
            const bf16x8 bh = *reinterpret_cast<const bf16x8*>(&Bh[bi]);
            const bf16x8 bl = *reinterpret_cast<const bf16x8*>(&Bl[bi]);
            acc[g] = __builtin_amdgcn_mfma_f32_16x16x32_bf16(ah, bh, acc[g], 0, 0, 0);
            acc[g] = __builtin_amdgcn_mfma_f32_16x16x32_bf16(ah, bl, acc[g], 0, 0, 0);
            acc[g] = __builtin_amdgcn_mfma_f32_16x16x32_bf16(al, bh, acc[g], 0, 0, 0);
        }
        __syncthreads();
    }
#pragma unroll
    for (int g = 0; g < 4; ++g)
#pragma unroll
        for (int q = 0; q < 4; ++q) {
            const int row = a0 + wm + (lane >> 4) * 4 + q;   // n
            const int col = b0 + g * 16 + (lane & 15);       // i
            atomicAdd(&WcT[(size_t)row * DM + col], SEQF * acc[g][q]);
        }
}

// ---- gemm_out: out[m][n] = sum_i X[m][i]*WcT[n][i] + cvec[n] + bo[n] ----
// 64x64 tile, K=512 (16 steps), grid 512 = 64 mt x 8 nt; WcT split on the fly.
// Swizzle: XCD owns 8 consecutive m-tiles x all n -> X panel 1MB + WcT 1MB in L2.
__global__ __launch_bounds__(256) void gemm_out(const float* __restrict__ X,
                                                const float* __restrict__ WcT,
                                                const float* __restrict__ cvec,
                                                const float* __restrict__ bo,
                                                float* __restrict__ out) {
    __shared__ ushort Ah[64 * LDR], Al[64 * LDR], Bh[64 * LDR], Bl[64 * LDR];
    const int d = blockIdx.x;                  // 0..511
    const int lin = (d & 7) * 64 + (d >> 3);
    const int mt = lin >> 3, nt = lin & 7;
    const int a0 = mt * 64, b0 = nt * 64;
    const int tid = threadIdx.x, wave = tid >> 6, lane = tid & 63;
    const int wm = wave * 16, fr = lane & 15, fs = (lane >> 4) * 8;

    f32x4 acc[4] = {};
    for (int t = 0; t < 16; ++t) {
        const int k0 = t * 32;
        stage64_f32(X, DM, a0, k0, Ah, Al, tid);
        stage64_f32(WcT, DM, b0, k0, Bh, Bl, tid);
        __syncthreads();
        const int ai = (wm + fr) * LDR + fs;
        const bf16x8 ah = *reinterpret_cast<const bf16x8*>(&Ah[ai]);
        const bf16x8 al = *reinterpret_cast<const bf16x8*>(&Al[ai]);
#pragma unroll
        for (int g = 0; g < 4; ++g) {
            const int bi = (g * 16 + fr) * LDR + fs;
            const bf16x8 bh = *reinterpret_cast<const bf16x8*>(&Bh[bi]);
            const bf16x8 bl = *reinterpret_cast<const bf16x8*>(&Bl[bi]);
            acc[g] = __builtin_amdgcn_mfma_f32_16x16x32_bf16(ah, bh, acc[g], 0, 0, 0);
            acc[g] = __builtin_amdgcn_mfma_f32_16x16x32_bf16(ah, bl, acc[g], 0, 0, 0);
            acc[g] = __builtin_amdgcn_mfma_f32_16x16x32_bf16(al, bh, acc[g], 0, 0, 0);
        }
        __syncthreads();
    }
#pragma unroll
    for (int g = 0; g < 4; ++g) {
        const int n = b0 + g * 16 + (lane & 15);
        const float cb = cvec[n] + bo[n];
#pragma unroll
        for (int q = 0; q < 4; ++q) {
            const int m = a0 + wm + (lane >> 4) * 4 + q;
            out[(size_t)m * DM + n] = acc[g][q] + cb;
        }
    }
}

extern "C" void kernel_launch(void* const* d_in, const int* in_sizes, int n_in,
                              void* d_out, int out_size, void* d_ws, size_t ws_size,
                              hipStream_t stream) {
    // inputs: 0 input, 1 mask, 2 Wq, 3 bq, 4 Wk, 5 bk, 6 Wv, 7 bv, 8 Wo, 9 bo
    const float* input = (const float*)d_in[0];
    const float* Wv    = (const float*)d_in[6];
    const float* bv    = (const float*)d_in[7];
    const float* Wo    = (const float*)d_in[8];
    const float* bo    = (const float*)d_in[9];
    float* out = (float*)d_out;

    ushort* WoTh = (ushort*)d_ws;                      // 4 MB
    ushort* WoTl = WoTh + (size_t)DM * HC;             // 4 MB
    float*  WcT  = (float*)(WoTl + (size_t)DM * HC);   // 1 MB fp32
    float*  cvec = WcT + (size_t)DM * DM;              // 2 KB

    hipMemsetAsync(WcT, 0, (size_t)DM * DM * 4 + DM * 4, stream);  // WcT + cvec

    prep_wo<<<dim3(64, 8), 256, 0, stream>>>(Wo, bv, WoTh, WoTl, cvec);
    gemm_wcT<<<512, 256, 0, stream>>>(WoTh, WoTl, Wv, WcT);
    gemm_out<<<512, 256, 0, stream>>>(input, WcT, cvec, bo, out);
}